// Round 9
// baseline (459.597 us; speedup 1.0000x reference)
//
#include <hip/hip_runtime.h>
#include <hip/hip_bf16.h>
#include <stdint.h>

#define GN 8192
#define GF 128
#define NEG_SLOPE 0.2f
#define BIGM 700.0f       // exp(-700) == 0.0f: masked entries vanish exactly

typedef __attribute__((ext_vector_type(8))) short bf16x8;
typedef __attribute__((ext_vector_type(4))) float f32x4;

__device__ __forceinline__ unsigned fkey(float f) {
    unsigned u = __float_as_uint(f);
    return (u & 0x80000000u) ? ~u : (u | 0x80000000u);
}
__device__ __forceinline__ float funkey(unsigned k) {
    unsigned b = (k & 0x80000000u) ? (k & 0x7FFFFFFFu) : ~k;
    return __uint_as_float(b);
}
__device__ __forceinline__ unsigned short bf16rne(float f) {
    unsigned u = __float_as_uint(f);
    return (unsigned short)((u + 0x7FFFu + ((u >> 16) & 1u)) >> 16);
}
// pack two fp32 -> two bf16 (round-half-up) in one v_perm
__device__ __forceinline__ unsigned packbf(float lo, float hi) {
    return __builtin_amdgcn_perm(__float_as_uint(hi) + 0x8000u,
                                 __float_as_uint(lo) + 0x8000u, 0x07060302u);
}
// async global->LDS DMA, 16 B/lane: per-lane global addr, wave-uniform LDS base
__device__ __forceinline__ void dma16(const unsigned short* g, unsigned short* l) {
    __builtin_amdgcn_global_load_lds(
        (const __attribute__((address_space(1))) unsigned int*)g,
        (__attribute__((address_space(3))) unsigned int*)l, 16, 0, 0);
}

// K1: x' = x@W + b (fp32); writes xpt in SWIZZLED MFMA-fragment order:
// elem(j, f) at [chunk=j/64][fg=f/16][half=(j%64)/32][q4=(j%32)/8][m16=f%16][jj=j%8]
// so a k2 B-tile (64 cols x 128 feats) is one contiguous 16 KB region in
// exact fragment order (DMA-able as 16 x 1KB segments).
__global__ __launch_bounds__(256) void gat_k1(
    const float* __restrict__ x, const float* __restrict__ w,
    const float* __restrict__ bias, const float* __restrict__ phi,
    unsigned short* __restrict__ xpt, float* __restrict__ s_src,
    float* __restrict__ s_dst)
{
    __shared__ float Xl[16][132];
    __shared__ float Wl[32][132];
    __shared__ unsigned short TR[128][24];
    const int tid = threadIdx.x;
    const int i0 = blockIdx.x * 16;

    #pragma unroll
    for (int q = 0; q < 2; q++) {                 // stage 16x128 x tile
        int flat = (q * 256 + tid) * 4;
        int r = flat >> 7, c = flat & 127;
        *(float4*)&Xl[r][c] = *(const float4*)&x[(size_t)(i0 + r) * GF + c];
    }

    const int rid = tid >> 5;          // 0..7 -> rows 2rid, 2rid+1
    const int c0  = (tid & 31) * 4;    // 4 consecutive features

    float acc[2][4] = {};
    for (int kc = 0; kc < 4; kc++) {   // W staged in 32-row chunks
        __syncthreads();
        #pragma unroll
        for (int q = 0; q < 4; q++) {
            int flat = (q * 256 + tid) * 4;
            int kk = flat >> 7, c = flat & 127;
            *(float4*)&Wl[kk][c] = *(const float4*)&w[(size_t)(kc * 32 + kk) * GF + c];
        }
        __syncthreads();
        #pragma unroll
        for (int k = 0; k < 32; k++) {
            float4 wv = *(const float4*)&Wl[k][c0];
            #pragma unroll
            for (int m = 0; m < 2; m++) {
                float xv = Xl[rid * 2 + m][kc * 32 + k];
                acc[m][0] = fmaf(xv, wv.x, acc[m][0]);
                acc[m][1] = fmaf(xv, wv.y, acc[m][1]);
                acc[m][2] = fmaf(xv, wv.z, acc[m][2]);
                acc[m][3] = fmaf(xv, wv.w, acc[m][3]);
            }
        }
    }

    float b4[4], p1[4], p2[4];
    #pragma unroll
    for (int q = 0; q < 4; q++) {
        b4[q] = bias[c0 + q];
        p1[q] = phi[c0 + q];
        p2[q] = phi[GF + c0 + q];
    }
    #pragma unroll
    for (int m = 0; m < 2; m++) {
        float ps = 0.f, pd = 0.f;
        #pragma unroll
        for (int q = 0; q < 4; q++) {
            float v = acc[m][q] + b4[q];
            ps = fmaf(v, p1[q], ps);
            pd = fmaf(v, p2[q], pd);
            TR[c0 + q][rid * 2 + m] = bf16rne(v);   // LDS transpose staging
        }
        #pragma unroll
        for (int s = 16; s >= 1; s >>= 1) {
            ps += __shfl_xor(ps, s, 64);
            pd += __shfl_xor(pd, s, 64);
        }
        if ((tid & 31) == 0) {
            s_src[i0 + rid * 2 + m] = ps;
            s_dst[i0 + rid * 2 + m] = pd;
        }
    }
    __syncthreads();
    {   // swizzled store: thread -> (feature f, node-octet oct), 16B each
        const int f = tid >> 1, oct = tid & 1;
        const int fg = f >> 4, mf = f & 15;
        const int chunk = i0 >> 6;
        const int half  = (i0 >> 5) & 1;
        const int q4b   = (((i0 & 31) >> 3)) + oct;   // {0,2}+oct
        const size_t base = (size_t)chunk * 8192 + fg * 1024 + half * 512
                          + q4b * 128 + mf * 8;
        *(uint4*)&xpt[base] = *(const uint4*)&TR[f][oct * 8];
    }
}

// K1b: D = max(s_dst). 8 blocks -> only 8 same-address atomics.
__global__ __launch_bounds__(256) void gat_k1b(
    const float* __restrict__ s_dst, unsigned* __restrict__ Dkey)
{
    __shared__ float sm[4];
    const int tid = threadIdx.x;
    const int idx = (blockIdx.x * 256 + tid) * 4;
    float4 v = *(const float4*)&s_dst[idx];
    float m = fmaxf(fmaxf(v.x, v.y), fmaxf(v.z, v.w));
    #pragma unroll
    for (int s = 32; s >= 1; s >>= 1) m = fmaxf(m, __shfl_xor(m, s, 64));
    if ((tid & 63) == 0) sm[tid >> 6] = m;
    __syncthreads();
    if (tid == 0) {
        m = fmaxf(fmaxf(sm[0], sm[1]), fmaxf(sm[2], sm[3]));
        atomicMax(Dkey, fkey(m));
    }
}

// K2: cooperative flash GAT (m97-style barrier pipeline).
// Block = 16 rows, 256 threads; ALL waves process the same 64-col chunk per
// iter; wave w owns output features [32w, 32w+32) -> acc is 8 VGPRs, each
// output element owned by ONE wave (no cross-wave O reduce, no atomics).
// B tile (16 KB, swizzled) double-buffered via cooperative global_load_lds;
// DMA issued AFTER the barrier (race-free dbuf; drained at the next barrier,
// where the mandatory vmcnt(0)-before-s_barrier is load-bearing, not waste).
// P double-buffered in LDS (one barrier per iter). adj/s_dst prefetched in
// registers one iter ahead. LDS 37 KB -> 4 blocks/CU = 16 waves (2x prior
// latency hiding); per-iter drains overlap other blocks' compute.
__global__ __launch_bounds__(256) void gat_k2(
    const float* __restrict__ adj, const unsigned short* __restrict__ xpt,
    const float* __restrict__ s_src, const float* __restrict__ s_dst,
    const unsigned* __restrict__ Dkey, float* __restrict__ out)
{
    __shared__ unsigned short Bt[2][8192];    // 2 x 16 KB swizzled B tiles
    __shared__ unsigned short Pt[2][16 * 68]; // P dbuf, row stride 68 shorts
    __shared__ float Zl[16];

    const int tid  = threadIdx.x;
    const int wave = tid >> 6, lane = tid & 63;
    const int m16  = lane & 15, q4 = lane >> 4;
    const int r    = tid >> 4;        // P row this thread computes (0..15)
    const int c4   = tid & 15;        // col quad within 64-col chunk
    const int i0   = blockIdx.x * 16;
    const int irow = i0 + r;

    const float D  = funkey(*Dkey);
    const float si = s_src[irow];
    const float t0 = si + D;
    const float mneg = -fmaxf(t0, NEG_SLOPE * t0);   // -Mi >= -(row max) bound
    const float base = mneg - BIGM;

    const float* arow = adj + (size_t)irow * GN + c4 * 4;
    const float* drow = s_dst + c4 * 4;

    f32x4 acc0 = {0.f, 0.f, 0.f, 0.f};
    f32x4 acc1 = {0.f, 0.f, 0.f, 0.f};
    float z = 0.f;

    // ---- prologue: DMA tile 0 -> Bt[0]; adj/s_dst regs for t=0
    {
        const unsigned short* gb = xpt + (size_t)(wave * 4) * 512 + lane * 8;
        unsigned short* lb = &Bt[0][(wave * 4) * 512];
        #pragma unroll
        for (int k = 0; k < 4; k++) dma16(gb + k * 512, lb + k * 512);
    }
    float4 aCur = *(const float4*)arow;
    float4 dCur = *(const float4*)drow;
    float4 aNxt = aCur, dNxt = dCur;

    #pragma unroll 1
    for (int t = 0; t < 128; t++) {
        const int cbase = t * 64;

        // ---- phase A: P(t) from registers -> Pt[t&1]
        {
            float p[4];
            #pragma unroll
            for (int q = 0; q < 4; q++) {
                const float tt = si + (&dCur.x)[q];
                const float lr = fmaxf(tt, NEG_SLOPE * tt);
                float zz = fmaf((&aCur.x)[q], BIGM, lr + base);
                if (cbase + c4 * 4 + q == irow) zz = lr + mneg;  // self-loop
                p[q] = __expf(zz);
            }
            z += (p[0] + p[1]) + (p[2] + p[3]);
            *(uint2*)&Pt[t & 1][r * 68 + c4 * 4] =
                make_uint2(packbf(p[0], p[1]), packbf(p[2], p[3]));
        }

        __syncthreads();   // drains DMA(t) [B ready] + orders P write/read

        // ---- phase B: issue DMA(t+1) + reg prefetch, then MFMA on tile t
        if (t < 127) {
            const int nb = cbase + 64;
            const unsigned short* gb = xpt + (size_t)(nb >> 6) * 8192
                                     + (size_t)(wave * 4) * 512 + lane * 8;
            unsigned short* lb = &Bt[(t + 1) & 1][(wave * 4) * 512];
            #pragma unroll
            for (int k = 0; k < 4; k++) dma16(gb + k * 512, lb + k * 512);
            aNxt = *(const float4*)(arow + nb);
            dNxt = *(const float4*)(drow + nb);
        }

        const unsigned short* Pb = Pt[t & 1];
        const bf16x8 af0 = *(const bf16x8*)&Pb[m16 * 68 + q4 * 8];        // k 0..31
        const bf16x8 af1 = *(const bf16x8*)&Pb[m16 * 68 + 32 + q4 * 8];   // k 32..63
        const unsigned short* Bb = Bt[t & 1];
        {   // wave's feature groups fg = 2*wave, 2*wave+1
            const unsigned short* b0p = &Bb[(wave * 2 + 0) * 1024 + lane * 8];
            const unsigned short* b1p = &Bb[(wave * 2 + 1) * 1024 + lane * 8];
            const bf16x8 b00 = *(const bf16x8*)b0p;
            const bf16x8 b01 = *(const bf16x8*)(b0p + 512);
            const bf16x8 b10 = *(const bf16x8*)b1p;
            const bf16x8 b11 = *(const bf16x8*)(b1p + 512);
            acc0 = __builtin_amdgcn_mfma_f32_16x16x32_bf16(af0, b00, acc0, 0, 0, 0);
            acc0 = __builtin_amdgcn_mfma_f32_16x16x32_bf16(af1, b01, acc0, 0, 0, 0);
            acc1 = __builtin_amdgcn_mfma_f32_16x16x32_bf16(af0, b10, acc1, 0, 0, 0);
            acc1 = __builtin_amdgcn_mfma_f32_16x16x32_bf16(af1, b11, acc1, 0, 0, 0);
        }

        aCur = aNxt; dCur = dNxt;
    }

    // ---- Z: reduce over the 16 threads (same wave) sharing row r
    z += __shfl_xor(z, 1, 64);
    z += __shfl_xor(z, 2, 64);
    z += __shfl_xor(z, 4, 64);
    z += __shfl_xor(z, 8, 64);
    if (c4 == 0) Zl[r] = z;
    __syncthreads();

    // ---- direct store: C layout col=m16 (feature), row=q4*4+v
    #pragma unroll
    for (int v = 0; v < 4; v++) {
        const int row = q4 * 4 + v;
        const float zi = 1.0f / Zl[row];
        float* orow = out + (size_t)(i0 + row) * GF + wave * 32 + m16;
        orow[0]  = acc0[v] * zi;
        orow[16] = acc1[v] * zi;
    }
}

extern "C" void kernel_launch(void* const* d_in, const int* in_sizes, int n_in,
                              void* d_out, int out_size, void* d_ws, size_t ws_size,
                              hipStream_t stream)
{
    (void)in_sizes; (void)n_in; (void)out_size; (void)ws_size;
    const float* adj  = (const float*)d_in[0];
    const float* x    = (const float*)d_in[1];
    const float* w    = (const float*)d_in[2];
    const float* bias = (const float*)d_in[3];
    const float* phi  = (const float*)d_in[4];
    float* out = (float*)d_out;

    char* ws = (char*)d_ws;
    unsigned short* xpt = (unsigned short*)ws;             // 2 MB bf16 x' swizzled
    float* s_src = (float*)(ws + (size_t)GF * GN * 2);     // 32 KB
    float* s_dst = s_src + GN;                             // 32 KB
    unsigned* Dkey = (unsigned*)(s_dst + GN);              // 4 B

    hipMemsetAsync(Dkey, 0, sizeof(unsigned), stream);
    gat_k1 <<<GN / 16, 256, 0, stream>>>(x, w, bias, phi, xpt, s_src, s_dst);
    gat_k1b<<<8, 256, 0, stream>>>(s_dst, Dkey);
    gat_k2 <<<GN / 16, 256, 0, stream>>>(adj, xpt, s_src, s_dst, Dkey, out);
}

// Round 10
// 424.623 us; speedup vs baseline: 1.0824x; 1.0824x over previous
//
#include <hip/hip_runtime.h>
#include <hip/hip_bf16.h>
#include <stdint.h>

#define GN 8192
#define GF 128
#define NEG_SLOPE 0.2f
#define BIGM 700.0f       // exp(-700) == 0.0f: masked entries vanish exactly

typedef __attribute__((ext_vector_type(8))) short bf16x8;
typedef __attribute__((ext_vector_type(4))) float f32x4;

__device__ __forceinline__ unsigned fkey(float f) {
    unsigned u = __float_as_uint(f);
    return (u & 0x80000000u) ? ~u : (u | 0x80000000u);
}
__device__ __forceinline__ float funkey(unsigned k) {
    unsigned b = (k & 0x80000000u) ? (k & 0x7FFFFFFFu) : ~k;
    return __uint_as_float(b);
}
__device__ __forceinline__ unsigned short bf16rne(float f) {
    unsigned u = __float_as_uint(f);
    return (unsigned short)((u + 0x7FFFu + ((u >> 16) & 1u)) >> 16);
}
// pack two fp32 -> two bf16 (round-half-up) in one v_perm
__device__ __forceinline__ unsigned packbf(float lo, float hi) {
    return __builtin_amdgcn_perm(__float_as_uint(hi) + 0x8000u,
                                 __float_as_uint(lo) + 0x8000u, 0x07060302u);
}
// async global->LDS DMA, 16 B/lane: per-lane global addr, wave-uniform LDS base
__device__ __forceinline__ void dma16(const unsigned short* g, unsigned short* l) {
    __builtin_amdgcn_global_load_lds(
        (const __attribute__((address_space(1))) unsigned int*)g,
        (__attribute__((address_space(3))) unsigned int*)l, 16, 0, 0);
}

// K1: x' = x@W + b (fp32); writes xpt in SWIZZLED MFMA-fragment order:
// elem(j, f) at [chunk=j/64][fg=f/16][half=(j%64)/32][q4=(j%32)/8][m16=f%16][jj=j%8]
// so a k2 B-tile (64 cols x 128 feats) is one contiguous 16 KB region in
// exact fragment order (DMA-able as 16 x 1KB segments).
__global__ __launch_bounds__(256) void gat_k1(
    const float* __restrict__ x, const float* __restrict__ w,
    const float* __restrict__ bias, const float* __restrict__ phi,
    unsigned short* __restrict__ xpt, float* __restrict__ s_src,
    float* __restrict__ s_dst)
{
    __shared__ float Xl[16][132];
    __shared__ float Wl[32][132];
    __shared__ unsigned short TR[128][24];
    const int tid = threadIdx.x;
    const int i0 = blockIdx.x * 16;

    #pragma unroll
    for (int q = 0; q < 2; q++) {                 // stage 16x128 x tile
        int flat = (q * 256 + tid) * 4;
        int r = flat >> 7, c = flat & 127;
        *(float4*)&Xl[r][c] = *(const float4*)&x[(size_t)(i0 + r) * GF + c];
    }

    const int rid = tid >> 5;          // 0..7 -> rows 2rid, 2rid+1
    const int c0  = (tid & 31) * 4;    // 4 consecutive features

    float acc[2][4] = {};
    for (int kc = 0; kc < 4; kc++) {   // W staged in 32-row chunks
        __syncthreads();
        #pragma unroll
        for (int q = 0; q < 4; q++) {
            int flat = (q * 256 + tid) * 4;
            int kk = flat >> 7, c = flat & 127;
            *(float4*)&Wl[kk][c] = *(const float4*)&w[(size_t)(kc * 32 + kk) * GF + c];
        }
        __syncthreads();
        #pragma unroll
        for (int k = 0; k < 32; k++) {
            float4 wv = *(const float4*)&Wl[k][c0];
            #pragma unroll
            for (int m = 0; m < 2; m++) {
                float xv = Xl[rid * 2 + m][kc * 32 + k];
                acc[m][0] = fmaf(xv, wv.x, acc[m][0]);
                acc[m][1] = fmaf(xv, wv.y, acc[m][1]);
                acc[m][2] = fmaf(xv, wv.z, acc[m][2]);
                acc[m][3] = fmaf(xv, wv.w, acc[m][3]);
            }
        }
    }

    float b4[4], p1[4], p2[4];
    #pragma unroll
    for (int q = 0; q < 4; q++) {
        b4[q] = bias[c0 + q];
        p1[q] = phi[c0 + q];
        p2[q] = phi[GF + c0 + q];
    }
    #pragma unroll
    for (int m = 0; m < 2; m++) {
        float ps = 0.f, pd = 0.f;
        #pragma unroll
        for (int q = 0; q < 4; q++) {
            float v = acc[m][q] + b4[q];
            ps = fmaf(v, p1[q], ps);
            pd = fmaf(v, p2[q], pd);
            TR[c0 + q][rid * 2 + m] = bf16rne(v);   // LDS transpose staging
        }
        #pragma unroll
        for (int s = 16; s >= 1; s >>= 1) {
            ps += __shfl_xor(ps, s, 64);
            pd += __shfl_xor(pd, s, 64);
        }
        if ((tid & 31) == 0) {
            s_src[i0 + rid * 2 + m] = ps;
            s_dst[i0 + rid * 2 + m] = pd;
        }
    }
    __syncthreads();
    {   // swizzled store: thread -> (feature f, node-octet oct), 16B each
        const int f = tid >> 1, oct = tid & 1;
        const int fg = f >> 4, mf = f & 15;
        const int chunk = i0 >> 6;
        const int half  = (i0 >> 5) & 1;
        const int q4b   = (((i0 & 31) >> 3)) + oct;   // {0,2}+oct
        const size_t base = (size_t)chunk * 8192 + fg * 1024 + half * 512
                          + q4b * 128 + mf * 8;
        *(uint4*)&xpt[base] = *(const uint4*)&TR[f][oct * 8];
    }
}

// K1b: D = max(s_dst). 8 blocks -> only 8 same-address atomics.
__global__ __launch_bounds__(256) void gat_k1b(
    const float* __restrict__ s_dst, unsigned* __restrict__ Dkey)
{
    __shared__ float sm[4];
    const int tid = threadIdx.x;
    const int idx = (blockIdx.x * 256 + tid) * 4;
    float4 v = *(const float4*)&s_dst[idx];
    float m = fmaxf(fmaxf(v.x, v.y), fmaxf(v.z, v.w));
    #pragma unroll
    for (int s = 32; s >= 1; s >>= 1) m = fmaxf(m, __shfl_xor(m, s, 64));
    if ((tid & 63) == 0) sm[tid >> 6] = m;
    __syncthreads();
    if (tid == 0) {
        m = fmaxf(fmaxf(sm[0], sm[1]), fmaxf(sm[2], sm[3]));
        atomicMax(Dkey, fkey(m));
    }
}

// K2: cooperative flash GAT, j-split 2-way for occupancy.
// Grid 1024: block (ib=bx>>1, jh=bx&1) does rows ib*16..+16 x cols
// jh*4096..+4096 (64 iters of 64-col chunks). LDS 37.4 KB -> 4 blocks/CU =
// 4 waves/SIMD: per-iter barrier drains of one block are filled by the other
// three blocks' compute. Wave w owns output features [32w,32w+32) (acc = 8
// VGPRs, no cross-wave O reduce). B tile (16 KB swizzled) double-buffered
// via cooperative global_load_lds issued right after the barrier (race-free;
// drained at the next barrier). Partial O via atomicAdd into zeroed out;
// partial Z into zbuf; k3 normalizes.
__global__ __launch_bounds__(256) void gat_k2(
    const float* __restrict__ adj, const unsigned short* __restrict__ xpt,
    const float* __restrict__ s_src, const float* __restrict__ s_dst,
    const unsigned* __restrict__ Dkey, float* __restrict__ outp,
    float* __restrict__ zbuf)
{
    __shared__ unsigned short Bt[2][8192];    // 2 x 16 KB swizzled B tiles
    __shared__ unsigned short Pt[2][16 * 68]; // P dbuf, row stride 68 shorts

    const int tid  = threadIdx.x;
    const int wave = tid >> 6, lane = tid & 63;
    const int m16  = lane & 15, q4 = lane >> 4;
    const int r    = tid >> 4;        // P row this thread computes (0..15)
    const int c4   = tid & 15;        // col quad within 64-col chunk
    const int ib   = blockIdx.x >> 1, jh = blockIdx.x & 1;
    const int i0   = ib * 16;
    const int irow = i0 + r;
    const int j0   = jh * 4096;

    const float D  = funkey(*Dkey);
    const float si = s_src[irow];
    const float t0 = si + D;
    const float mneg = -fmaxf(t0, NEG_SLOPE * t0);   // -Mi >= -(row max) bound
    const float base = mneg - BIGM;

    const float* arow = adj + (size_t)irow * GN + j0 + c4 * 4;
    const float* drow = s_dst + j0 + c4 * 4;

    f32x4 acc0 = {0.f, 0.f, 0.f, 0.f};
    f32x4 acc1 = {0.f, 0.f, 0.f, 0.f};
    float z = 0.f;

    // ---- prologue: DMA tile 0 -> Bt[0]; adj/s_dst regs for t=0
    {
        const unsigned short* gb = xpt + (size_t)(j0 >> 6) * 8192
                                 + (size_t)(wave * 4) * 512 + lane * 8;
        unsigned short* lb = &Bt[0][(wave * 4) * 512];
        #pragma unroll
        for (int k = 0; k < 4; k++) dma16(gb + k * 512, lb + k * 512);
    }
    float4 aCur = *(const float4*)arow;
    float4 dCur = *(const float4*)drow;
    float4 aNxt = aCur, dNxt = dCur;

    #pragma unroll 1
    for (int t = 0; t < 64; t++) {
        const int cbase = j0 + t * 64;

        // ---- phase A: P(t) from registers -> Pt[t&1]
        {
            float p[4];
            #pragma unroll
            for (int q = 0; q < 4; q++) {
                const float tt = si + (&dCur.x)[q];
                const float lr = fmaxf(tt, NEG_SLOPE * tt);
                float zz = fmaf((&aCur.x)[q], BIGM, lr + base);
                if (cbase + c4 * 4 + q == irow) zz = lr + mneg;  // self-loop
                p[q] = __expf(zz);
            }
            z += (p[0] + p[1]) + (p[2] + p[3]);
            *(uint2*)&Pt[t & 1][r * 68 + c4 * 4] =
                make_uint2(packbf(p[0], p[1]), packbf(p[2], p[3]));
        }

        __syncthreads();   // drains DMA(t) [B ready] + orders P write/read

        // ---- phase B: issue DMA(t+1) + reg prefetch, then MFMA on tile t
        if (t < 63) {
            const int nb = cbase + 64;
            const unsigned short* gb = xpt + (size_t)(nb >> 6) * 8192
                                     + (size_t)(wave * 4) * 512 + lane * 8;
            unsigned short* lb = &Bt[(t + 1) & 1][(wave * 4) * 512];
            #pragma unroll
            for (int k = 0; k < 4; k++) dma16(gb + k * 512, lb + k * 512);
            aNxt = *(const float4*)(arow + t * 64 + 64);
            dNxt = *(const float4*)(drow + t * 64 + 64);
        }

        const unsigned short* Pb = Pt[t & 1];
        const bf16x8 af0 = *(const bf16x8*)&Pb[m16 * 68 + q4 * 8];        // k 0..31
        const bf16x8 af1 = *(const bf16x8*)&Pb[m16 * 68 + 32 + q4 * 8];   // k 32..63
        const unsigned short* Bb = Bt[t & 1];
        {   // wave's feature groups fg = 2*wave, 2*wave+1
            const unsigned short* b0p = &Bb[(wave * 2 + 0) * 1024 + lane * 8];
            const unsigned short* b1p = &Bb[(wave * 2 + 1) * 1024 + lane * 8];
            const bf16x8 b00 = *(const bf16x8*)b0p;
            const bf16x8 b01 = *(const bf16x8*)(b0p + 512);
            const bf16x8 b10 = *(const bf16x8*)b1p;
            const bf16x8 b11 = *(const bf16x8*)(b1p + 512);
            acc0 = __builtin_amdgcn_mfma_f32_16x16x32_bf16(af0, b00, acc0, 0, 0, 0);
            acc0 = __builtin_amdgcn_mfma_f32_16x16x32_bf16(af1, b01, acc0, 0, 0, 0);
            acc1 = __builtin_amdgcn_mfma_f32_16x16x32_bf16(af0, b10, acc1, 0, 0, 0);
            acc1 = __builtin_amdgcn_mfma_f32_16x16x32_bf16(af1, b11, acc1, 0, 0, 0);
        }

        aCur = aNxt; dCur = dNxt;
    }

    // ---- Z partial: reduce over the 16 threads (same wave) sharing row r
    z += __shfl_xor(z, 1, 64);
    z += __shfl_xor(z, 2, 64);
    z += __shfl_xor(z, 4, 64);
    z += __shfl_xor(z, 8, 64);
    if (c4 == 0) atomicAdd(&zbuf[irow], z);

    // ---- O partial: C layout col=m16 (feature), row=q4*4+v
    #pragma unroll
    for (int v = 0; v < 4; v++) {
        const int row = q4 * 4 + v;
        float* orow = outp + (size_t)(i0 + row) * GF + wave * 32 + m16;
        atomicAdd(orow,      acc0[v]);
        atomicAdd(orow + 16, acc1[v]);
    }
}

// K3: out /= Z (row-wise), vectorized
__global__ __launch_bounds__(256) void gat_k3(
    float* __restrict__ outp, const float* __restrict__ zbuf)
{
    const int idx4 = blockIdx.x * 256 + threadIdx.x;
    const int row = idx4 >> 5;                  // 32 float4 per 128-f row
    f32x4 v = *(f32x4*)&outp[(size_t)idx4 * 4];
    v *= (1.0f / zbuf[row]);
    *(f32x4*)&outp[(size_t)idx4 * 4] = v;
}

extern "C" void kernel_launch(void* const* d_in, const int* in_sizes, int n_in,
                              void* d_out, int out_size, void* d_ws, size_t ws_size,
                              hipStream_t stream)
{
    (void)in_sizes; (void)n_in; (void)out_size; (void)ws_size;
    const float* adj  = (const float*)d_in[0];
    const float* x    = (const float*)d_in[1];
    const float* w    = (const float*)d_in[2];
    const float* bias = (const float*)d_in[3];
    const float* phi  = (const float*)d_in[4];
    float* out = (float*)d_out;

    char* ws = (char*)d_ws;
    unsigned short* xpt = (unsigned short*)ws;             // 2 MB bf16 x' swizzled
    float* s_src = (float*)(ws + (size_t)GF * GN * 2);     // 32 KB
    float* s_dst = s_src + GN;                             // 32 KB
    float* zbuf  = s_dst + GN;                             // 32 KB
    unsigned* Dkey = (unsigned*)(zbuf + GN);               // 4 B

    hipMemsetAsync(Dkey, 0, sizeof(unsigned), stream);
    hipMemsetAsync(zbuf, 0, GN * sizeof(float), stream);
    hipMemsetAsync(out, 0, (size_t)GN * GF * sizeof(float), stream);
    gat_k1 <<<GN / 16, 256, 0, stream>>>(x, w, bias, phi, xpt, s_src, s_dst);
    gat_k1b<<<8, 256, 0, stream>>>(s_dst, Dkey);
    gat_k2 <<<GN / 16 * 2, 256, 0, stream>>>(adj, xpt, s_src, s_dst, Dkey, out, zbuf);
    gat_k3 <<<GN * GF / 4 / 256, 256, 0, stream>>>(out, zbuf);
}